// Round 6
// baseline (112.679 us; speedup 1.0000x reference)
//
#include <hip/hip_runtime.h>

#define TSTEPS 64
#define NI 8192
#define NO 8192
#define DECAY 0.9375f
#define NDET 64               // detect blocks

typedef __attribute__((ext_vector_type(8))) short bf16x8;   // MFMA A/B frag (4 VGPR)
typedef __attribute__((ext_vector_type(4))) float f32x4;    // MFMA C/D frag

// ---------------------------------------------------------------------------
// Kernel 0 (verbatim round-5, passing): detect uint8 vs int32 storage of the
// bool spike raster. 64 blocks, each scans 8 KB of the first 512 KB.
// ---------------------------------------------------------------------------
__global__ __launch_bounds__(256) void detect_kernel(const unsigned int* sp, int* flags) {
    __shared__ int any;
    if (threadIdx.x == 0) any = 0;
    __syncthreads();
    int local = 0;
    const unsigned int* p = sp + blockIdx.x * 2048;       // 8 KB per block
    #pragma unroll
    for (int i = 0; i < 8; ++i) {
        unsigned int w = p[i * 256 + threadIdx.x];
        if (w & 0xFFFFFF00u) local = 1;
    }
    if (local) atomicOr(&any, 1);
    __syncthreads();
    if (threadIdx.x == 0) flags[blockIdx.x] = any;        // 1 => uint8 layout
}

// ---------------------------------------------------------------------------
// Kernel 1 (verbatim round-5, passing): spikes -> row-major bf16 S[t][k].
// ---------------------------------------------------------------------------
__global__ __launch_bounds__(256) void convert_kernel(const void* sp, const int* flags,
                                                      unsigned short* __restrict__ Sbf) {
    int f = 0;
    for (int i = 0; i < NDET; ++i) f |= flags[i];
    const int gid = blockIdx.x * 256 + threadIdx.x;   // 0..65535
    const int t   = gid >> 10;
    const int k0  = (gid & 1023) * 8;
    unsigned h[8];
    #pragma unroll
    for (int e = 0; e < 8; ++e) {
        int gi = t * NI + k0 + e;
        bool b;
        if (f) b = ((const unsigned char*)sp)[gi] != 0;
        else   b = ((const int*)sp)[gi] != 0;
        h[e] = b ? 0x3F80u : 0u;                      // bf16(1.0) = 0x3F80
    }
    uint4 v;
    v.x = h[0] | (h[1] << 16);
    v.y = h[2] | (h[3] << 16);
    v.z = h[4] | (h[5] << 16);
    v.w = h[6] | (h[7] << 16);
    *(uint4*)(Sbf + (size_t)t * NI + k0) = v;
}

// ---------------------------------------------------------------------------
// Triple split (UNCHANGED, passing): w = hi + mid + lo, error <= 2^-22 |w|.
// ---------------------------------------------------------------------------
__device__ __forceinline__ void split3(const float4& x, const float4& y,
                                       bf16x8& hi, bf16x8& mid, bf16x8& lo) {
    float v[8] = {x.x, x.y, x.z, x.w, y.x, y.y, y.z, y.w};
    #pragma unroll
    for (int e = 0; e < 8; ++e) {
        unsigned b   = __float_as_uint(v[e]);
        unsigned hb  = b & 0xFFFF0000u;
        float    r1  = v[e] - __uint_as_float(hb);                // exact
        unsigned r1b = __float_as_uint(r1);
        unsigned mb  = r1b & 0xFFFF0000u;
        float    r2  = r1 - __uint_as_float(mb);                  // exact
        unsigned r2b = __float_as_uint(r2);
        unsigned lr  = (r2b + 0x7FFFu + ((r2b >> 16) & 1u)) >> 16; // RNE bf16
        hi[e]  = (short)(b >> 16);
        mid[e] = (short)(mb >> 16);
        lo[e]  = (short)lr;
    }
}

// ---------------------------------------------------------------------------
// Kernel 2: FUSED gemm + K-reduce + LIF scan. One block = 16 neurons, all T,
// all K. 512 blocks x 512 threads (8 waves; 2 blocks/CU = 16 waves/CU, same
// TLP as round 5). Wave w: 16o x 64t over K-chunk [w*1024, w*1024+1024)
// using the proven triple-split MFMA path (1 M-tile x 4 N-tiles).
// Then: acc -> LDS red[8][16][66] (stride 66 => <=2-way bank alias, free),
// barrier, 512-thread deterministic w-sum into red[0], barrier, 16-thread
// in-LDS LIF scan writing spikes + final mempot straight to out.
// ---------------------------------------------------------------------------
__global__ __launch_bounds__(512, 4) void fused_kernel(const float* __restrict__ W,
                                                       const unsigned short* __restrict__ Sbf,
                                                       float* __restrict__ out) {
    __shared__ float red[8][16][66];

    const int tid  = threadIdx.x;
    const int w    = tid >> 6;          // wave 0..7 -> K-chunk
    const int lane = tid & 63;
    const int r16  = lane & 15;
    const int kg   = lane >> 4;
    const int o0   = blockIdx.x * 16;
    const int kbase = w * 1024 + kg * 8;

    f32x4 acc[4];
    #pragma unroll
    for (int n = 0; n < 4; ++n) acc[n] = (f32x4)0.f;

    const float* ap = W + (size_t)(o0 + r16) * NI + kbase;
    const unsigned short* bp[4];
    #pragma unroll
    for (int n = 0; n < 4; ++n)
        bp[n] = Sbf + (size_t)(n * 16 + r16) * NI + kbase;

    #pragma unroll 2
    for (int c = 0; c < 32; ++c) {      // 32 chunks of K=32 per wave
        bf16x8 Bf[4];
        #pragma unroll
        for (int n = 0; n < 4; ++n)
            Bf[n] = *(const bf16x8*)(bp[n] + c * 32);
        float4 a0 = *(const float4*)(ap + c * 32);
        float4 a1 = *(const float4*)(ap + c * 32 + 4);
        bf16x8 hi, mid, lo;
        split3(a0, a1, hi, mid, lo);
        #pragma unroll
        for (int n = 0; n < 4; ++n) {
            acc[n] = __builtin_amdgcn_mfma_f32_16x16x32_bf16(hi,  Bf[n], acc[n], 0, 0, 0);
            acc[n] = __builtin_amdgcn_mfma_f32_16x16x32_bf16(mid, Bf[n], acc[n], 0, 0, 0);
            acc[n] = __builtin_amdgcn_mfma_f32_16x16x32_bf16(lo,  Bf[n], acc[n], 0, 0, 0);
        }
    }

    // acc -> LDS per verified D-map: t(col) = n*16 + (lane&15), o = kg*4 + reg.
    #pragma unroll
    for (int n = 0; n < 4; ++n)
        #pragma unroll
        for (int r = 0; r < 4; ++r)
            red[w][kg * 4 + r][n * 16 + r16] = acc[n][r];
    __syncthreads();

    // Deterministic K-reduction: each thread owns 2 (o,t) cells, sums w=0..7
    // in fixed order. Writes only its own cells' red[0] slot (no hazards).
    #pragma unroll
    for (int i = tid; i < 1024; i += 512) {
        int o = i >> 6, t = i & 63;
        float s = 0.f;
        #pragma unroll
        for (int w2 = 0; w2 < 8; ++w2) s += red[w2][o][t];
        red[0][o][t] = s;
    }
    __syncthreads();

    // LIF scan: 16 threads, one neuron each, serial in t (inherent).
    if (tid < 16) {
        const int o = tid;
        float m = 0.f;
        out[o0 + o] = 0.f;                               // spike row 0
        #pragma unroll 4
        for (int t = 0; t < TSTEPS; ++t) {
            m += red[0][o][t];
            bool sp = (m >= 1.0f);
            out[(size_t)(t + 1) * NO + o0 + o] = sp ? 1.0f : 0.0f;
            m = sp ? (m - 1.0f) : m * DECAY;
        }
        out[(size_t)(TSTEPS + 1) * NO + o0 + o] = m;     // final mempot
    }
}

// ---------------------------------------------------------------------------
extern "C" void kernel_launch(void* const* d_in, const int* in_sizes, int n_in,
                              void* d_out, int out_size, void* d_ws, size_t ws_size,
                              hipStream_t stream) {
    const void*  spikes = d_in[0];
    const float* W      = (const float*)d_in[1];
    float*       out    = (float*)d_out;
    char*        ws     = (char*)d_ws;

    // ws layout: [flags 256 B][Sbf 1 MB]
    int*            flags = (int*)ws;
    unsigned short* Sbf   = (unsigned short*)(ws + 256);

    hipLaunchKernelGGL(detect_kernel,  dim3(NDET),    dim3(256), 0, stream,
                       (const unsigned int*)spikes, flags);
    hipLaunchKernelGGL(convert_kernel, dim3(256),     dim3(256), 0, stream,
                       spikes, flags, Sbf);
    hipLaunchKernelGGL(fused_kernel,   dim3(NO / 16), dim3(512), 0, stream,
                       W, Sbf, out);
}